// Round 20
// baseline (112.893 us; speedup 1.0000x reference)
//
#include <hip/hip_runtime.h>

typedef __attribute__((ext_vector_type(8))) short bf16x8;
typedef __attribute__((ext_vector_type(4))) float f32x4;
typedef __attribute__((ext_vector_type(8))) unsigned short u16x8;

#define BB 32
#define NN 1024
#define MM 256
#define HH 128

__device__ __forceinline__ unsigned short f2bf(float f) {
  union { float f; unsigned int u; } c; c.f = f;
  unsigned int u = c.u + 0x7fffu + ((c.u >> 16) & 1u);  // RNE
  return (unsigned short)(u >> 16);
}
__device__ __forceinline__ unsigned int cvtpk(float lo, float hi) {
  unsigned int r;
  asm("v_cvt_pk_bf16_f32 %0, %1, %2" : "=v"(r) : "v"(lo), "v"(hi));
  return r;
}
__device__ __forceinline__ float4 gload_f4(const float* p) {
  float4 r;
  asm volatile("global_load_dwordx4 %0, %1, off" : "=v"(r) : "v"(p));
  return r;
}
typedef __attribute__((address_space(3))) unsigned int as3_u32;
typedef const __attribute__((address_space(1))) unsigned int as1_u32;
__device__ __forceinline__ void gl_lds16(const void* g, void* l) {
  __builtin_amdgcn_global_load_lds((as1_u32*)g, (as3_u32*)l, 16, 0, 0);
}

// ---------- combined pre-pass: hT (bf16 [B][M][N]) + W1T/W2T ----------
__global__ __launch_bounds__(256)
void k_prep(const float* __restrict__ hg, unsigned short* __restrict__ hTg,
            const float* __restrict__ W1, const float* __restrict__ W2,
            unsigned short* __restrict__ W1T, unsigned short* __restrict__ W2T) {
  int bid = blockIdx.x;
  if (bid < BB * 64) {
    __shared__ unsigned short tile[64][65];
    int b = bid >> 6;
    int t = bid & 63;
    int k0 = (t >> 2) << 6;
    int m0 = (t & 3) << 6;
    int tt = threadIdx.x;
    {
      int r = tt >> 2;
      int cg = (tt & 3) << 4;
      const float* src = hg + (((size_t)b * NN + k0 + r) * MM + m0 + cg);
#pragma unroll
      for (int i = 0; i < 4; ++i) {
        float4 v = reinterpret_cast<const float4*>(src)[i];
        tile[r][cg + i * 4 + 0] = f2bf(v.x);
        tile[r][cg + i * 4 + 1] = f2bf(v.y);
        tile[r][cg + i * 4 + 2] = f2bf(v.z);
        tile[r][cg + i * 4 + 3] = f2bf(v.w);
      }
    }
    __syncthreads();
    {
      int mr = tt >> 2;
      int kc = (tt & 3) << 4;
      alignas(16) unsigned short tmp[16];
#pragma unroll
      for (int i = 0; i < 16; ++i) tmp[i] = tile[kc + i][mr];
      unsigned short* dst = hTg + (((size_t)b * MM + m0 + mr) * NN + k0 + kc);
      *reinterpret_cast<u16x8*>(dst)     = *reinterpret_cast<u16x8*>(tmp);
      *reinterpret_cast<u16x8*>(dst + 8) = *reinterpret_cast<u16x8*>(tmp + 8);
    }
  } else {
    int idx = (bid - BB * 64) * 256 + threadIdx.x;
    if (idx < MM * HH) {
      int hc = idx >> 8;
      int m  = idx & 255;
      W1T[idx] = f2bf(W1[m * HH + hc]);
    } else {
      int j = idx - MM * HH;
      int m  = j >> 7;
      int hd = j & 127;
      W2T[j] = f2bf(W2[hd * MM + m]);
    }
  }
}

// ---------------- fused main ----------------
// 512 blocks x 512 threads (8 waves = 2 row-halves x 4 col-quarters).
// Block tile 64 rows x 256 cols; per-wave 32x64; BK=64, 16 K-steps.
// r14 structure with the VGPR clamp REMOVED (r14's only failure was the
// (512,4) bound forcing VGPR=64 -> spill). A: DIRECT per-lane fragment
// loads (asm-volatile-pinned, 1 step ahead; vmcnt(0) at point of use).
// No A-LDS at all: deletes per-step ds_writes + 2/6 of ds_reads.
// H: verified gl_lds dbuf [256 cols][128B] ^(col&7)<<4, pre-swizzled src.
// Per step t: vmcnt(0)[A(t) regs landed] -> cvt A(t) -> issue H(t+1)
//   gl_lds + A(t+1) pinned -> consume -> vmcnt(8) [H(t+1) in LDS, A(t+1)
//   crosses the barrier in flight] -> lgkm-barrier. One barrier/step.
// LDS = 64KB H dbuf -> 2 blocks/CU (VGPR must stay <= 128; no bounds).
// Kld [64][512B]=32KB aliases HB0; Cld [64][256B]=16KB at +32K.
#define HB_(x) ((x) * 32768)
#define KLD 0
#define CLD 32768

#define PIPE_BARRIER() do { \
  asm volatile("s_waitcnt lgkmcnt(0)" ::: "memory"); \
  __builtin_amdgcn_s_barrier(); \
  asm volatile("" ::: "memory"); } while (0)
#define VMW(N) do { asm volatile("s_waitcnt vmcnt(" #N ")" ::: "memory"); \
  __builtin_amdgcn_sched_barrier(0); } while (0)

__global__ __launch_bounds__(512)
void k_fused(const float* __restrict__ Ag, const float* __restrict__ hg,
             const unsigned short* __restrict__ hTg,
             const unsigned short* __restrict__ W1Tg,
             const unsigned short* __restrict__ W2Tg,
             const float* __restrict__ b1g, const float* __restrict__ b2g,
             float* __restrict__ outg) {
  __shared__ __align__(16) char smem[65536];
  __shared__ float smax[64];

  const int tid  = threadIdx.x;
  const int lane = tid & 63;
  const int wid  = tid >> 6;       // 0..7
  const int wr   = wid >> 2;       // 0..1 row half (32 rows)
  const int wc   = wid & 3;        // 0..3 col quarter (64 cols)
  const int l15  = lane & 15;
  const int lg   = lane >> 4;      // 0..3

  const int bid = blockIdx.x;
  const int b   = bid & 31;        // batch-b blocks share bid%8 -> same XCD L2
  const int r0  = (bid >> 5) << 6; // 16 row-blocks of 64

  const float* Ab = Ag + ((size_t)b * NN + r0) * NN;
  const unsigned short* hTb = hTg + (size_t)b * MM * NN;

  // ---- A direct-fragment pointers: row wr*32+{0,16}+l15, k = kk*32+lg*8 ----
  const float* ap0 = Ab + (size_t)((wr << 5) + l15) * NN + (lg << 3);
  const float* ap1 = ap0 + (size_t)16 * NN;

  // ---- H staging (verified): [256 cols][128B], pre-swizzled source ----
  const unsigned short* baseH[4];
#pragma unroll
  for (int i = 0; i < 4; ++i) {
    int c = i * 512 + tid;           // 16B chunk id: [256 cols][8 chunks]
    int col = c >> 3, cic = c & 7;
    baseH[i] = hTb + (size_t)col * NN + ((cic ^ (col & 7)) << 3);
  }
  const int dstW = wid << 10;        // wave-uniform base (64 lanes x 16B)

#define STAGE_H(K0, HB)                                                      \
  do {                                                                       \
    _Pragma("unroll")                                                        \
    for (int i = 0; i < 4; ++i)                                              \
      gl_lds16(baseH[i] + (K0), smem + (HB) + dstW + i * 8192);              \
  } while (0)

  // pinned A prefetch regs: m{0,1} x kk{0,1} x half{lo,hi}
  float4 a00l, a00h, a01l, a01h, a10l, a10h, a11l, a11h;
#define ISSUE_A(K0)                                                          \
  do {                                                                       \
    a00l = gload_f4(ap0 + (K0));       a00h = gload_f4(ap0 + (K0) + 4);      \
    a01l = gload_f4(ap0 + (K0) + 32);  a01h = gload_f4(ap0 + (K0) + 36);     \
    a10l = gload_f4(ap1 + (K0));       a10h = gload_f4(ap1 + (K0) + 4);      \
    a11l = gload_f4(ap1 + (K0) + 32);  a11h = gload_f4(ap1 + (K0) + 36);     \
  } while (0)

  float pm0 = -1e30f, pm1 = -1e30f;
  bf16x8 af00, af01, af10, af11;
#define MAX8(L, H) fmaxf(fmaxf(fmaxf((L).x, (L).y), fmaxf((L).z, (L).w)),    \
                         fmaxf(fmaxf((H).x, (H).y), fmaxf((H).z, (H).w)))
#define CVT1(DST, L, H)                                                      \
  do {                                                                       \
    uint4 q = make_uint4(cvtpk((L).x, (L).y), cvtpk((L).z, (L).w),           \
                         cvtpk((H).x, (H).y), cvtpk((H).z, (H).w));          \
    DST = *reinterpret_cast<bf16x8*>(&q);                                    \
  } while (0)
#define CVT_A()                                                              \
  do {                                                                       \
    pm0 = fmaxf(pm0, fmaxf(MAX8(a00l, a00h), MAX8(a01l, a01h)));             \
    pm1 = fmaxf(pm1, fmaxf(MAX8(a10l, a10h), MAX8(a11l, a11h)));             \
    CVT1(af00, a00l, a00h); CVT1(af01, a01l, a01h);                          \
    CVT1(af10, a10l, a10h); CVT1(af11, a11l, a11h);                          \
  } while (0)

  f32x4 acc[2][4];
#pragma unroll
  for (int m = 0; m < 2; ++m)
#pragma unroll
    for (int n = 0; n < 4; ++n) acc[m][n] = f32x4{0.f, 0.f, 0.f, 0.f};

#define CONSUME(HB)                                                          \
  do {                                                                       \
    _Pragma("unroll")                                                        \
    for (int kk = 0; kk < 2; ++kk) {                                         \
      const int kb = (kk * 32 + (lg << 3)) * 2;                              \
      bf16x8 bh[4];                                                          \
      _Pragma("unroll")                                                      \
      for (int n = 0; n < 4; ++n) {                                          \
        int col = (wc << 6) + (n << 4) + l15;                                \
        bh[n] = *reinterpret_cast<const bf16x8*>(                            \
            smem + (HB) + col * 128 + (kb ^ ((col & 7) << 4)));              \
      }                                                                      \
      bf16x8 fa0 = kk ? af01 : af00;                                         \
      bf16x8 fa1 = kk ? af11 : af10;                                         \
      _Pragma("unroll")                                                      \
      for (int n = 0; n < 4; ++n) {                                          \
        acc[0][n] = __builtin_amdgcn_mfma_f32_16x16x32_bf16(fa0, bh[n],      \
                                                            acc[0][n], 0, 0, 0); \
        acc[1][n] = __builtin_amdgcn_mfma_f32_16x16x32_bf16(fa1, bh[n],      \
                                                            acc[1][n], 0, 0, 0); \
      }                                                                      \
    }                                                                        \
  } while (0)

  // ---- prologue: stage step 0 fully ----
  STAGE_H(0, HB_(0));
  ISSUE_A(0);
  VMW(0);
  __builtin_amdgcn_s_barrier();

  // ---- phase 1: 16 K-steps of 64, one barrier per step ----
#pragma unroll
  for (int t = 0; t < 16; ++t) {
    VMW(0);                                // A(t) regs landed
    CVT_A();                               // A(t) -> bf16 frags (+rowmax)
    if (t < 15) {
      STAGE_H((t + 1) * 64, (t & 1) ? HB_(0) : HB_(1));  // H first (4 gl_lds)
      ISSUE_A((t + 1) * 64);                             // A second (8 loads)
    }
    CONSUME((t & 1) ? HB_(1) : HB_(0));
    if (t < 15) {
      VMW(8);                              // H(t+1) in LDS; A(t+1) still flying
      PIPE_BARRIER();
    }
  }

  // ---- rowmax finalize: reduce over lg; wc==0 writes ----
  {
    float v0 = pm0, v1 = pm1;
    v0 = fmaxf(v0, __shfl_xor(v0, 16));
    v0 = fmaxf(v0, __shfl_xor(v0, 32));
    v1 = fmaxf(v1, __shfl_xor(v1, 16));
    v1 = fmaxf(v1, __shfl_xor(v1, 32));
    if (wc == 0 && lg == 0) {
      smax[(wr << 5) + l15]      = v0;
      smax[(wr << 5) + 16 + l15] = v1;
    }
  }
  __syncthreads();   // phase-1 LDS fully retired before aliasing

  // ---- write k tile (/3, bf16) -> Kld [64][512B] XOR ----
  {
    const float inv3 = 1.0f / 3.0f;
#pragma unroll
    for (int m = 0; m < 2; ++m)
#pragma unroll
      for (int n = 0; n < 4; ++n) {
        int col = (wc << 6) + (n << 4) + l15;
#pragma unroll
        for (int j = 0; j < 4; ++j) {
          int row = (wr << 5) + (m << 4) + (lg << 2) + j;
          *reinterpret_cast<unsigned short*>(smem + KLD + row * 512 +
                                             ((col * 2) ^ ((row & 7) << 4))) =
              f2bf(acc[m][n][j] * inv3);
        }
      }
  }
  __syncthreads();

  // ---- GEMM1: y[64][128] = k @ W1 (W1T fragments straight from L2) ----
  f32x4 acc1[2][2];
#pragma unroll
  for (int m = 0; m < 2; ++m)
#pragma unroll
    for (int n = 0; n < 2; ++n) acc1[m][n] = f32x4{0.f, 0.f, 0.f, 0.f};
  const int wcol1 = wc << 5;  // 0,32,64,96
#pragma unroll
  for (int kq = 0; kq < 8; ++kq) {
    bf16x8 af[2], bw[2];
#pragma unroll
    for (int m = 0; m < 2; ++m) {
      int row = (wr << 5) + (m << 4) + l15;
      af[m] = *reinterpret_cast<const bf16x8*>(smem + KLD + row * 512 +
              (((kq * 32 + (lg << 3)) * 2) ^ ((row & 7) << 4)));
    }
#pragma unroll
    for (int n = 0; n < 2; ++n) {
      int col = wcol1 + (n << 4) + l15;
      bw[n] = *reinterpret_cast<const bf16x8*>(W1Tg + (size_t)col * 256 +
                                               kq * 32 + (lg << 3));
    }
#pragma unroll
    for (int m = 0; m < 2; ++m)
#pragma unroll
      for (int n = 0; n < 2; ++n)
        acc1[m][n] = __builtin_amdgcn_mfma_f32_16x16x32_bf16(af[m], bw[n], acc1[m][n], 0, 0, 0);
  }
  __syncthreads();  // Kld fully read

  // ---- c = relu(y+b1) -> Cld [64][256B] XOR (disjoint from Kld) ----
  {
#pragma unroll
    for (int n = 0; n < 2; ++n) {
      int col = wcol1 + (n << 4) + l15;
      float bias = b1g[col];
#pragma unroll
      for (int m = 0; m < 2; ++m)
#pragma unroll
        for (int j = 0; j < 4; ++j) {
          int row = (wr << 5) + (m << 4) + (lg << 2) + j;
          float v = fmaxf(acc1[m][n][j] + bias, 0.f);
          *reinterpret_cast<unsigned short*>(smem + CLD + row * 256 +
                                             ((col * 2) ^ ((row & 7) << 4))) = f2bf(v);
        }
    }
  }
  __syncthreads();

  // ---- GEMM2: out2[64][256] = c @ W2 (W2T fragments from L2) ----
  f32x4 acc2[2][4];
#pragma unroll
  for (int m = 0; m < 2; ++m)
#pragma unroll
    for (int n = 0; n < 4; ++n) acc2[m][n] = f32x4{0.f, 0.f, 0.f, 0.f};
#pragma unroll
  for (int kq = 0; kq < 4; ++kq) {
    bf16x8 af[2], bw[4];
#pragma unroll
    for (int m = 0; m < 2; ++m) {
      int row = (wr << 5) + (m << 4) + l15;
      af[m] = *reinterpret_cast<const bf16x8*>(smem + CLD + row * 256 +
              (((kq * 32 + (lg << 3)) * 2) ^ ((row & 7) << 4)));
    }
#pragma unroll
    for (int n = 0; n < 4; ++n) {
      int col = (wc << 6) + (n << 4) + l15;
      bw[n] = *reinterpret_cast<const bf16x8*>(W2Tg + (size_t)col * 128 +
                                               kq * 32 + (lg << 3));
    }
#pragma unroll
    for (int m = 0; m < 2; ++m)
#pragma unroll
      for (int n = 0; n < 4; ++n)
        acc2[m][n] = __builtin_amdgcn_mfma_f32_16x16x32_bf16(af[m], bw[n], acc2[m][n], 0, 0, 0);
  }

  // ---- epilogue: out = (out2+b2)*mask + h*(1-mask) ----
  {
#pragma unroll
    for (int n = 0; n < 4; ++n) {
      int col = (wc << 6) + (n << 4) + l15;
      float b2v = b2g[col];
#pragma unroll
      for (int m = 0; m < 2; ++m)
#pragma unroll
        for (int j = 0; j < 4; ++j) {
          int row = (wr << 5) + (m << 4) + (lg << 2) + j;
          float kv = acc2[m][n][j] + b2v;
          float mask = smax[row];
          size_t gidx = ((size_t)b * NN + r0 + row) * MM + col;
          float hv = hg[gidx];
          outg[gidx] = kv * mask + hv * (1.f - mask);
        }
    }
  }
#undef CONSUME
#undef CVT_A
#undef CVT1
#undef MAX8
#undef ISSUE_A
#undef STAGE_H
}

extern "C" void kernel_launch(void* const* d_in, const int* in_sizes, int n_in,
                              void* d_out, int out_size, void* d_ws, size_t ws_size,
                              hipStream_t stream) {
  (void)in_sizes; (void)n_in; (void)out_size; (void)ws_size;
  const float* A  = (const float*)d_in[0];
  const float* h  = (const float*)d_in[1];
  const float* W1 = (const float*)d_in[2];
  const float* b1 = (const float*)d_in[3];
  const float* W2 = (const float*)d_in[4];
  const float* b2 = (const float*)d_in[5];
  float* out = (float*)d_out;

  unsigned short* hT  = (unsigned short*)d_ws;
  unsigned short* W1T = (unsigned short*)((char*)d_ws + (size_t)BB * MM * NN * 2);
  unsigned short* W2T = W1T + MM * HH;

  k_prep<<<BB * 64 + 256, 256, 0, stream>>>(h, hT, W1, W2, W1T, W2T);
  k_fused<<<BB * 16, 512, 0, stream>>>(A, h, hT, W1T, W2T, b1, b2, out);
}

// Round 21
// 57.889 us; speedup vs baseline: 1.9502x; 1.9502x over previous
//
#include <hip/hip_runtime.h>

typedef __attribute__((ext_vector_type(8))) short bf16x8;
typedef __attribute__((ext_vector_type(4))) float f32x4;
typedef __attribute__((ext_vector_type(8))) unsigned short u16x8;

#define BB 32
#define NN 1024
#define MM 256
#define HH 128

__device__ __forceinline__ unsigned short f2bf(float f) {
  union { float f; unsigned int u; } c; c.f = f;
  unsigned int u = c.u + 0x7fffu + ((c.u >> 16) & 1u);  // RNE
  return (unsigned short)(u >> 16);
}
__device__ __forceinline__ unsigned int cvtpk(float lo, float hi) {
  unsigned int r;
  asm("v_cvt_pk_bf16_f32 %0, %1, %2" : "=v"(r) : "v"(lo), "v"(hi));
  return r;
}
__device__ __forceinline__ float4 gload_f4(const float* p) {
  float4 r;
  asm volatile("global_load_dwordx4 %0, %1, off" : "=v"(r) : "v"(p));
  return r;
}
typedef __attribute__((address_space(3))) unsigned int as3_u32;
typedef const __attribute__((address_space(1))) unsigned int as1_u32;
__device__ __forceinline__ void gl_lds16(const void* g, void* l) {
  __builtin_amdgcn_global_load_lds((as1_u32*)g, (as3_u32*)l, 16, 0, 0);
}

// ---------- combined pre-pass: hT (bf16 [B][M][N]) + W1T/W2T ----------
__global__ __launch_bounds__(256)
void k_prep(const float* __restrict__ hg, unsigned short* __restrict__ hTg,
            const float* __restrict__ W1, const float* __restrict__ W2,
            unsigned short* __restrict__ W1T, unsigned short* __restrict__ W2T) {
  int bid = blockIdx.x;
  if (bid < BB * 64) {
    __shared__ unsigned short tile[64][65];
    int b = bid >> 6;
    int t = bid & 63;
    int k0 = (t >> 2) << 6;
    int m0 = (t & 3) << 6;
    int tt = threadIdx.x;
    {
      int r = tt >> 2;
      int cg = (tt & 3) << 4;
      const float* src = hg + (((size_t)b * NN + k0 + r) * MM + m0 + cg);
#pragma unroll
      for (int i = 0; i < 4; ++i) {
        float4 v = reinterpret_cast<const float4*>(src)[i];
        tile[r][cg + i * 4 + 0] = f2bf(v.x);
        tile[r][cg + i * 4 + 1] = f2bf(v.y);
        tile[r][cg + i * 4 + 2] = f2bf(v.z);
        tile[r][cg + i * 4 + 3] = f2bf(v.w);
      }
    }
    __syncthreads();
    {
      int mr = tt >> 2;
      int kc = (tt & 3) << 4;
      alignas(16) unsigned short tmp[16];
#pragma unroll
      for (int i = 0; i < 16; ++i) tmp[i] = tile[kc + i][mr];
      unsigned short* dst = hTg + (((size_t)b * MM + m0 + mr) * NN + k0 + kc);
      *reinterpret_cast<u16x8*>(dst)     = *reinterpret_cast<u16x8*>(tmp);
      *reinterpret_cast<u16x8*>(dst + 8) = *reinterpret_cast<u16x8*>(tmp + 8);
    }
  } else {
    int idx = (bid - BB * 64) * 256 + threadIdx.x;
    if (idx < MM * HH) {
      int hc = idx >> 8;
      int m  = idx & 255;
      W1T[idx] = f2bf(W1[m * HH + hc]);
    } else {
      int j = idx - MM * HH;
      int m  = j >> 7;
      int hd = j & 127;
      W2T[j] = f2bf(W2[hd * MM + m]);
    }
  }
}

// ---------------- fused main (champion r17/r18 structure) ----------------
// 512 blocks x 512 threads (8 waves = 2 row-halves x 4 col-quarters).
// Block tile 64 rows x 256 cols; per-wave 32x64; BK=64, 16 K-steps.
// A: contiguous-staged (4 rows x 256B runs/wave-instr), pinned asm loads,
//    2-deep X/Y reg sets, LDS dbuf; H: gl_lds dbuf, pre-swizzled source.
// One barrier/step; counted waits never target loads younger than ~1 step.
// LDS (81920 B = 80 KiB -> 2 blocks/CU): H0@0 H1@32K A0@64K A1@72K;
// phase2 alias: Kld@0, Cld@32K, smax@64K (A0 dead after phase 1).
#define HB0 0
#define HB1 32768
#define AB0 65536
#define AB1 73728
#define KLD 0
#define CLD 32768
#define SMAXOFF 65536

#define PIPE_BARRIER() do { \
  asm volatile("s_waitcnt lgkmcnt(0)" ::: "memory"); \
  __builtin_amdgcn_s_barrier(); \
  asm volatile("" ::: "memory"); } while (0)

#define VMW(N) do { asm volatile("s_waitcnt vmcnt(" #N ")" ::: "memory"); \
  __builtin_amdgcn_sched_barrier(0); } while (0)

__global__ __launch_bounds__(512)
void k_fused(const float* __restrict__ Ag, const float* __restrict__ hg,
             const unsigned short* __restrict__ hTg,
             const unsigned short* __restrict__ W1Tg,
             const unsigned short* __restrict__ W2Tg,
             const float* __restrict__ b1g, const float* __restrict__ b2g,
             float* __restrict__ outg) {
  __shared__ __align__(16) char smem[81920];
  float* smax = reinterpret_cast<float*>(smem + SMAXOFF);

  const int tid  = threadIdx.x;
  const int lane = tid & 63;
  const int wid  = tid >> 6;       // 0..7
  const int wr   = wid >> 2;       // 0..1 (row half, 32 rows)
  const int wc   = wid & 3;        // 0..3 (col quarter, 64 cols)
  const int l15  = lane & 15;
  const int lg   = lane >> 4;      // 0..3

  const int bid = blockIdx.x;
  const int b   = bid & 31;        // same-batch blocks share bid%8 -> same XCD
  const int r0  = (bid >> 5) << 6; // 16 row-blocks of 64

  const float* Ab = Ag + ((size_t)b * NN + r0) * NN;
  const unsigned short* hTb = hTg + (size_t)b * MM * NN;

  // ---- A staging (verified contiguous map): row = i*32+(tid>>4), 16B
  // chunk tid&15; wave-instr = 4 rows x 256B contiguous runs ----
  const int arow0 = tid >> 4;
  const int akc   = tid & 15;
  const float* apA0 = Ab + (size_t)arow0        * NN + (akc << 2);
  const float* apA1 = Ab + (size_t)(32 + arow0) * NN + (akc << 2);

  // ---- H staging (verified): [256 cols][128B], pre-swizzled source ----
  const unsigned short* baseH[4];
#pragma unroll
  for (int i = 0; i < 4; ++i) {
    int c = i * 512 + tid;
    int col = c >> 3, cic = c & 7;
    baseH[i] = hTb + (size_t)col * NN + ((cic ^ (col & 7)) << 3);
  }
  const int ldsW = wid << 10;

#define STAGE_H(K0, HB)                                                     \
  do {                                                                      \
    _Pragma("unroll")                                                       \
    for (int i = 0; i < 4; ++i)                                             \
      gl_lds16(baseH[i] + (K0), smem + (HB) + ldsW + i * 8192);             \
  } while (0)

  // two pinned A register sets (X/Y), 8 VGPR each
  float4 rAX0, rAX1, rAY0, rAY1;
#define ISSUE_AX(K0) do { rAX0 = gload_f4(apA0 + (K0));                     \
                          rAX1 = gload_f4(apA1 + (K0)); } while (0)
#define ISSUE_AY(K0) do { rAY0 = gload_f4(apA0 + (K0));                     \
                          rAY1 = gload_f4(apA1 + (K0)); } while (0)

  float pm0 = -1e30f, pm1 = -1e30f;
#define CVTWR(AB, R0, R1)                                                   \
  do {                                                                      \
    pm0 = fmaxf(pm0, fmaxf(fmaxf((R0).x, (R0).y), fmaxf((R0).z, (R0).w)));  \
    pm1 = fmaxf(pm1, fmaxf(fmaxf((R1).x, (R1).y), fmaxf((R1).z, (R1).w)));  \
    uint2 q0 = make_uint2(cvtpk((R0).x, (R0).y), cvtpk((R0).z, (R0).w));    \
    uint2 q1 = make_uint2(cvtpk((R1).x, (R1).y), cvtpk((R1).z, (R1).w));    \
    *reinterpret_cast<uint2*>(smem + (AB) + (arow0)      * 128 +            \
                              ((akc << 3) ^ ((arow0 & 7) << 4))) = q0;      \
    *reinterpret_cast<uint2*>(smem + (AB) + (32 + arow0) * 128 +            \
                              ((akc << 3) ^ ((arow0 & 7) << 4))) = q1;      \
  } while (0)

  f32x4 acc[2][4];
#pragma unroll
  for (int m = 0; m < 2; ++m)
#pragma unroll
    for (int n = 0; n < 4; ++n) acc[m][n] = f32x4{0.f, 0.f, 0.f, 0.f};

#define CONSUME(AB, HB)                                                     \
  do {                                                                      \
    _Pragma("unroll")                                                       \
    for (int kk = 0; kk < 2; ++kk) {                                        \
      const int kb = (kk * 32 + (lg << 3)) * 2;                             \
      bf16x8 af[2], bh[4];                                                  \
      _Pragma("unroll")                                                     \
      for (int m = 0; m < 2; ++m) {                                         \
        int row = (wr << 5) + (m << 4) + l15;                               \
        af[m] = *reinterpret_cast<const bf16x8*>(                           \
            smem + (AB) + row * 128 + (kb ^ ((row & 7) << 4)));             \
      }                                                                     \
      _Pragma("unroll")                                                     \
      for (int n = 0; n < 4; ++n) {                                         \
        int col = (wc << 6) + (n << 4) + l15;                               \
        bh[n] = *reinterpret_cast<const bf16x8*>(                           \
            smem + (HB) + col * 128 + (kb ^ ((col & 7) << 4)));             \
      }                                                                     \
      _Pragma("unroll")                                                     \
      for (int m = 0; m < 2; ++m)                                           \
        _Pragma("unroll")                                                   \
        for (int n = 0; n < 4; ++n)                                         \
          acc[m][n] = __builtin_amdgcn_mfma_f32_16x16x32_bf16(af[m], bh[n], \
                                                              acc[m][n], 0, 0, 0); \
    }                                                                       \
  } while (0)

  // ---- prologue: H(0)+A(0), cvt A(0)->AB0; issue A(1)->Y ----
  STAGE_H(0, HB0);
  ISSUE_AX(0);
  VMW(0);
  CVTWR(AB0, rAX0, rAX1);
  ISSUE_AY(64);
  PIPE_BARRIER();

  // ---- phase 1: 16 K-steps of 64, one barrier/step, 2-deep A pipeline ----
#pragma unroll
  for (int t = 0; t < 16; ++t) {
    if (t < 15) STAGE_H((t + 1) * 64, (t & 1) ? HB0 : HB1);
    if (t < 14) {
      if (t & 1) ISSUE_AY((t + 2) * 64);
      else       ISSUE_AX((t + 2) * 64);
    }
    CONSUME((t & 1) ? AB1 : AB0, (t & 1) ? HB1 : HB0);
    if (t < 15) {
      if (t < 14) VMW(6); else VMW(4);
      if (t & 1) CVTWR(AB0, rAX0, rAX1);
      else       CVTWR(AB1, rAY0, rAY1);
      if (t < 14) VMW(2); else VMW(0);
      PIPE_BARRIER();
    }
  }

  // ---- rowmax finalize: reduce over lane bits 0-3 (16 staging lanes/row) ----
  {
    float v0 = pm0, v1 = pm1;
#pragma unroll
    for (int s = 1; s < 16; s <<= 1) {
      v0 = fmaxf(v0, __shfl_xor(v0, s));
      v1 = fmaxf(v1, __shfl_xor(v1, s));
    }
    if ((tid & 15) == 0) {
      smax[arow0]      = v0;
      smax[32 + arow0] = v1;
    }
  }
  __syncthreads();   // phase-1 LDS fully retired before aliasing

  // ---- write k tile (/3, bf16) -> Kld [64][512B] XOR @0 (alias H0) ----
  {
    const float inv3 = 1.0f / 3.0f;
#pragma unroll
    for (int m = 0; m < 2; ++m)
#pragma unroll
      for (int n = 0; n < 4; ++n) {
        int col = (wc << 6) + (n << 4) + l15;
#pragma unroll
        for (int j = 0; j < 4; ++j) {
          int row = (wr << 5) + (m << 4) + (lg << 2) + j;
          *reinterpret_cast<unsigned short*>(smem + KLD + row * 512 +
                                             ((col * 2) ^ ((row & 7) << 4))) =
              f2bf(acc[m][n][j] * inv3);
        }
      }
  }
  __syncthreads();

  // ---- GEMM1: y[64][128] = k @ W1 (W1T fragments straight from L2) ----
  f32x4 acc1[2][2];
#pragma unroll
  for (int m = 0; m < 2; ++m)
#pragma unroll
    for (int n = 0; n < 2; ++n) acc1[m][n] = f32x4{0.f, 0.f, 0.f, 0.f};
  const int wcol1 = wc << 5;  // 0,32,64,96
#pragma unroll
  for (int kq = 0; kq < 8; ++kq) {
    bf16x8 af[2], bw[2];
#pragma unroll
    for (int m = 0; m < 2; ++m) {
      int row = (wr << 5) + (m << 4) + l15;
      af[m] = *reinterpret_cast<const bf16x8*>(smem + KLD + row * 512 +
              (((kq * 32 + (lg << 3)) * 2) ^ ((row & 7) << 4)));
    }
#pragma unroll
    for (int n = 0; n < 2; ++n) {
      int col = wcol1 + (n << 4) + l15;
      bw[n] = *reinterpret_cast<const bf16x8*>(W1Tg + (size_t)col * 256 +
                                               kq * 32 + (lg << 3));
    }
#pragma unroll
    for (int m = 0; m < 2; ++m)
#pragma unroll
      for (int n = 0; n < 2; ++n)
        acc1[m][n] = __builtin_amdgcn_mfma_f32_16x16x32_bf16(af[m], bw[n], acc1[m][n], 0, 0, 0);
  }
  __syncthreads();  // Kld fully read

  // ---- c = relu(y+b1) -> Cld [64][256B] XOR @32K (alias H1, disjoint) ----
  {
#pragma unroll
    for (int n = 0; n < 2; ++n) {
      int col = wcol1 + (n << 4) + l15;
      float bias = b1g[col];
#pragma unroll
      for (int m = 0; m < 2; ++m)
#pragma unroll
        for (int j = 0; j < 4; ++j) {
          int row = (wr << 5) + (m << 4) + (lg << 2) + j;
          float v = fmaxf(acc1[m][n][j] + bias, 0.f);
          *reinterpret_cast<unsigned short*>(smem + CLD + row * 256 +
                                             ((col * 2) ^ ((row & 7) << 4))) = f2bf(v);
        }
    }
  }
  __syncthreads();

  // ---- GEMM2: out2[64][256] = c @ W2 (W2T fragments from L2) ----
  f32x4 acc2[2][4];
#pragma unroll
  for (int m = 0; m < 2; ++m)
#pragma unroll
    for (int n = 0; n < 4; ++n) acc2[m][n] = f32x4{0.f, 0.f, 0.f, 0.f};
#pragma unroll
  for (int kq = 0; kq < 4; ++kq) {
    bf16x8 af[2], bw[4];
#pragma unroll
    for (int m = 0; m < 2; ++m) {
      int row = (wr << 5) + (m << 4) + l15;
      af[m] = *reinterpret_cast<const bf16x8*>(smem + CLD + row * 256 +
              (((kq * 32 + (lg << 3)) * 2) ^ ((row & 7) << 4)));
    }
#pragma unroll
    for (int n = 0; n < 4; ++n) {
      int col = (wc << 6) + (n << 4) + l15;
      bw[n] = *reinterpret_cast<const bf16x8*>(W2Tg + (size_t)col * 128 +
                                               kq * 32 + (lg << 3));
    }
#pragma unroll
    for (int m = 0; m < 2; ++m)
#pragma unroll
      for (int n = 0; n < 4; ++n)
        acc2[m][n] = __builtin_amdgcn_mfma_f32_16x16x32_bf16(af[m], bw[n], acc2[m][n], 0, 0, 0);
  }

  // ---- epilogue: out = (out2+b2)*mask + h*(1-mask) ----
  {
#pragma unroll
    for (int n = 0; n < 4; ++n) {
      int col = (wc << 6) + (n << 4) + l15;
      float b2v = b2g[col];
#pragma unroll
      for (int m = 0; m < 2; ++m)
#pragma unroll
        for (int j = 0; j < 4; ++j) {
          int row = (wr << 5) + (m << 4) + (lg << 2) + j;
          float kv = acc2[m][n][j] + b2v;
          float mask = smax[row];
          size_t gidx = ((size_t)b * NN + r0 + row) * MM + col;
          float hv = hg[gidx];
          outg[gidx] = kv * mask + hv * (1.f - mask);
        }
    }
  }
#undef CONSUME
#undef CVTWR
#undef ISSUE_AX
#undef ISSUE_AY
#undef STAGE_H
}

extern "C" void kernel_launch(void* const* d_in, const int* in_sizes, int n_in,
                              void* d_out, int out_size, void* d_ws, size_t ws_size,
                              hipStream_t stream) {
  (void)in_sizes; (void)n_in; (void)out_size; (void)ws_size;
  const float* A  = (const float*)d_in[0];
  const float* h  = (const float*)d_in[1];
  const float* W1 = (const float*)d_in[2];
  const float* b1 = (const float*)d_in[3];
  const float* W2 = (const float*)d_in[4];
  const float* b2 = (const float*)d_in[5];
  float* out = (float*)d_out;

  unsigned short* hT  = (unsigned short*)d_ws;
  unsigned short* W1T = (unsigned short*)((char*)d_ws + (size_t)BB * MM * NN * 2);
  unsigned short* W2T = W1T + MM * HH;

  k_prep<<<BB * 64 + 256, 256, 0, stream>>>(h, hT, W1, W2, W1T, W2T);
  k_fused<<<BB * 16, 512, 0, stream>>>(A, h, hT, W1T, W2T, b1, b2, out);
}